// Round 18
// baseline (143.682 us; speedup 1.0000x reference)
//
#include <hip/hip_runtime.h>
#include <hip/hip_bf16.h>
#include <cstdint>
#include <cstddef>

// B=8, T=2048, D=128 causal dual-mode attention.
// logits = Qeff . K^T with Qeff[t][d] = -alpha*scale*q[t][d] + (1-alpha)*scale*q[t][(d+1)%D]
// (feature-roll moved from K onto Q), then causal softmax, then @V.
//
// R18: LDS-pipe relief. V fragments live in REGISTERS (global->reg, 1 tile
// ahead, T14 async-split); K double-buffered in LDS with stage-before-compute
// and ONE raw s_barrier + counted vmcnt(8) per step (V prefetch rides across).
// Q from bf16 qbf prepass (R11). Accounting/combine = R17 (unified bf16
// partials). 2-wave blocks, 32 q-rows, KVBLK=32, SEGT=8.

typedef __attribute__((ext_vector_type(8))) short short8;
typedef __attribute__((ext_vector_type(4))) float f32x4;

#define T_DIM 2048
#define D_DIM 128
#define B_DIM 8
#define SEGT 8              // 32-kv tiles per segment
#define MLSLOTS_PER_B 288   // sum over c=0..63 of nseg(c), nseg=(c+8)>>3
#define LOG2E 1.4426950408889634f

__device__ __forceinline__ unsigned short f2bf(float f) {
  unsigned u = __builtin_bit_cast(unsigned, f);
  u += 0x7FFFu + ((u >> 16) & 1u);          // RNE
  return (unsigned short)(u >> 16);
}
__device__ __forceinline__ float bf2f(unsigned short u) {
  return __uint_as_float(((unsigned)u) << 16);
}
__device__ __forceinline__ void gload_lds16(const void* g, void* l) {
  __builtin_amdgcn_global_load_lds(
      (const __attribute__((address_space(1))) unsigned int*)g,
      (__attribute__((address_space(3))) unsigned int*)l, 16, 0, 0);
}

// ---------------- fused prepass: K->bf16, Qeff->bf16 (log2e folded), V^T->bf16 ----------------
__global__ __launch_bounds__(256) void prep_all(
    const float* __restrict__ q, const float* __restrict__ k, const float* __restrict__ v,
    const float* __restrict__ modep,
    unsigned short* __restrict__ qbf, unsigned short* __restrict__ kbf,
    unsigned short* __restrict__ vt)
{
  __shared__ unsigned short tile[64 * 136];   // V rows as bf16, pitch 136 shorts
  const int b = blockIdx.x, s0 = blockIdx.y * 64;
  const int tid = threadIdx.x;
  const float alpha = 1.f / (1.f + __expf(-modep[0]));
  const float scale = 0.08838834764831845f;
  const float ca = -alpha * scale * LOG2E, cb = (1.f - alpha) * scale * LOG2E;

#pragma unroll
  for (int u = 0; u < 4; ++u) {
    int c = u * 256 + tid;                    // 1024 chunks = 64 rows x 16
    int r = c >> 4, c8 = c & 15;
    size_t row = (size_t)b * T_DIM + s0 + r;
    float4 ka = *(const float4*)(k + row * D_DIM + c8 * 8);
    float4 kb2 = *(const float4*)(k + row * D_DIM + c8 * 8 + 4);
    short8 ko = { (short)f2bf(ka.x), (short)f2bf(ka.y), (short)f2bf(ka.z), (short)f2bf(ka.w),
                  (short)f2bf(kb2.x), (short)f2bf(kb2.y), (short)f2bf(kb2.z), (short)f2bf(kb2.w) };
    *(short8*)(kbf + row * D_DIM + c8 * 8) = ko;
    const float* qr = q + row * D_DIM;
    float e[9];
    float4 f0 = *(const float4*)(qr + c8 * 8);
    float4 f1 = *(const float4*)(qr + c8 * 8 + 4);
    e[0] = f0.x; e[1] = f0.y; e[2] = f0.z; e[3] = f0.w;
    e[4] = f1.x; e[5] = f1.y; e[6] = f1.z; e[7] = f1.w;
    e[8] = qr[(c8 * 8 + 8) & 127];
    short8 qo;
#pragma unroll
    for (int j = 0; j < 8; ++j) qo[j] = (short)f2bf(ca * e[j] + cb * e[j + 1]);
    *(short8*)(qbf + row * D_DIM + c8 * 8) = qo;
    float4 va = *(const float4*)(v + row * D_DIM + c8 * 8);
    float4 vb2 = *(const float4*)(v + row * D_DIM + c8 * 8 + 4);
    short8 vo = { (short)f2bf(va.x), (short)f2bf(va.y), (short)f2bf(va.z), (short)f2bf(va.w),
                  (short)f2bf(vb2.x), (short)f2bf(vb2.y), (short)f2bf(vb2.z), (short)f2bf(vb2.w) };
    *(short8*)(tile + r * 136 + c8 * 8) = vo;
  }
  __syncthreads();
#pragma unroll
  for (int u = 0; u < 8; ++u) {
    int c = u * 256 + tid;                    // 2048 = 128 d x 16 s-quads
    int d = c >> 4, sq = c & 15;
    ushort4 o = { tile[(sq * 4 + 0) * 136 + d], tile[(sq * 4 + 1) * 136 + d],
                  tile[(sq * 4 + 2) * 136 + d], tile[(sq * 4 + 3) * 136 + d] };
    *(ushort4*)(vt + ((size_t)b * D_DIM + d) * T_DIM + s0 + sq * 4) = o;
  }
}

// ---------------- main attention: K dbuf LDS, V in regs (1-ahead), 1 barrier/step ----------------
// LDS 18,432B: K dbuf 2x8KB ([32 r][256B] swz) | P per-wave 2x1KB ([16][64B] swz)
__global__ __launch_bounds__(128, 4) void attn_kernel(
    const unsigned short* __restrict__ qbf, const unsigned short* __restrict__ kbf,
    const unsigned short* __restrict__ vt, float* __restrict__ out,
    unsigned short* __restrict__ po, float* __restrict__ ml)
{
  __shared__ uint4 smem4[1152];               // 18,432 B
  char* smem = (char*)smem4;
  const int tid = threadIdx.x;
  const int w = tid >> 6, lane = tid & 63;
  const int t16 = lane & 15, g = lane >> 4;
  const int b = blockIdx.x;                   // linear%8==b -> batch pinned to XCD
  const int c = 63 - (int)blockIdx.y;         // 32-row q-chunk, big first
  const int s = blockIdx.z;
  const int nt = c + 1;                       // causal 32-kv tiles
  const int nseg = (nt + SEGT - 1) >> 3;
  if (s >= nseg) return;
  const int t0 = s * SEGT;
  const int t1 = min(nt, t0 + SEGT);
  const int qb16 = c * 32 + w * 16;           // wave's first q-row

  char* pw = smem + 16384 + w * 1024;         // per-wave P [16][64B], swizzled
  const unsigned short* kbase = kbf + (size_t)b * T_DIM * D_DIM;
  const unsigned short* vbase = vt + (size_t)b * D_DIM * T_DIM;

  // ---- Qeff fragments from qbf (A-layout: row=t16, k=dd*32+g*8+i) ----
  short8 qf[4];
  {
    const unsigned short* qr = qbf + ((size_t)b * T_DIM + qb16 + t16) * D_DIM + g * 8;
#pragma unroll
    for (int dd = 0; dd < 4; ++dd) qf[dd] = *(const short8*)(qr + dd * 32);
  }

  f32x4 acc[8];                               // C: row q = 4g+r, col d = 16dt+t16
#pragma unroll
  for (int dt = 0; dt < 8; ++dt) acc[dt] = (f32x4){0.f, 0.f, 0.f, 0.f};
  float mrun[4] = {-1e30f, -1e30f, -1e30f, -1e30f};   // per q-row 4g+r, log2 units
  float lsum[4] = {0.f, 0.f, 0.f, 0.f};

  // ---- K staging (this wave's half: 16 rows, 8 gload_lds total per wave... 4) ----
  auto stageK = [&](int cur, int kt) {
    const int kv0 = kt * 32;
    char* kb = smem + cur * 8192;
#pragma unroll
    for (int u = 0; u < 4; ++u) {
      int s_loc = w * 16 + u * 4 + (lane >> 4);
      int slot = (lane & 15) ^ (s_loc & 7);
      gload_lds16(kbase + (size_t)(kv0 + s_loc) * D_DIM + slot * 8,
                  kb + w * 4096 + u * 1024);
    }
  };
  // ---- V fragment load (global -> regs, R7-verified pattern) ----
  auto vload = [&](short8* vbuf, int kt) {
    const int kv0 = kt * 32;
#pragma unroll
    for (int dt = 0; dt < 8; ++dt)
      vbuf[dt] = *(const short8*)(vbase + (size_t)(dt * 16 + t16) * T_DIM + kv0 + g * 8);
  };

  short8 vcur[8], vnext[8];
  stageK(0, t0);
  vload(vcur, t0);
  asm volatile("s_waitcnt vmcnt(0)" ::: "memory");
  __builtin_amdgcn_s_barrier();
  __builtin_amdgcn_sched_barrier(0);
  int cur = 0;

  for (int kt = t0; kt < t1; ++kt) {
    const int kv0 = kt * 32;
    const bool more = (kt + 1 < t1);
    if (more) {
      stageK(cur ^ 1, kt + 1);                // 4 gload_lds (per wave)
      vload(vnext, kt + 1);                   // 8 global loads, ride across barrier
    }
    char* kb = smem + cur * 8192;

    // ---- S = Qeff . K^T : sj[jt][r] = S[q=qb16+4g+r][kv=kv0+16jt+t16] ----
    f32x4 sj[2];
#pragma unroll
    for (int jt = 0; jt < 2; ++jt) {
      int srow = jt * 16 + t16;
      int rb = srow * 256, swz = (srow & 7) << 4;
      f32x4 sc = (f32x4){0.f, 0.f, 0.f, 0.f};
#pragma unroll
      for (int dd = 0; dd < 4; ++dd) {
        short8 kf = *(const short8*)(kb + ((rb + dd * 64 + g * 16) ^ swz));
        sc = __builtin_amdgcn_mfma_f32_16x16x32_bf16(qf[dd], kf, sc, 0, 0, 0);
      }
      sj[jt] = sc;
    }

    // ---- causal mask (only the global last tile kt==c can be partial) ----
    if (kt == c) {
#pragma unroll
      for (int jt = 0; jt < 2; ++jt) {
        int sg = kv0 + jt * 16 + t16;
#pragma unroll
        for (int r = 0; r < 4; ++r) {
          int tg = qb16 + 4 * g + r;
          if (sg > tg) sj[jt][r] = -1e30f;
        }
      }
    }

    // ---- defer-max online softmax (log2 domain) ----
    float lm[4];
    int ok = 1;
#pragma unroll
    for (int r = 0; r < 4; ++r) {
      lm[r] = fmaxf(sj[0][r], sj[1][r]);
      ok &= (lm[r] <= mrun[r] + 11.0f);
    }
    if (!__all(ok)) {
#pragma unroll
      for (int r = 0; r < 4; ++r) {
        float tm = lm[r];
        tm = fmaxf(tm, __shfl_xor(tm, 1));
        tm = fmaxf(tm, __shfl_xor(tm, 2));
        tm = fmaxf(tm, __shfl_xor(tm, 4));
        tm = fmaxf(tm, __shfl_xor(tm, 8));
        float mnew = fmaxf(mrun[r], tm);
        float corr = exp2f(mrun[r] - mnew);
        mrun[r] = mnew;
        lsum[r] *= corr;
#pragma unroll
        for (int dt = 0; dt < 8; ++dt) acc[dt][r] *= corr;
      }
    }

    // ---- P = exp2(S-m), per-lane partial sums, P -> LDS (swizzled) ----
#pragma unroll
    for (int jt = 0; jt < 2; ++jt)
#pragma unroll
      for (int r = 0; r < 4; ++r) {
        float p = exp2f(sj[jt][r] - mrun[r]);
        lsum[r] += p;
        int row = 4 * g + r;                  // q-row local
        *(unsigned short*)(pw + row * 64 + ((jt * 32 + t16 * 2) ^ ((row >> 2) << 4))) = f2bf(p);
      }

    // ---- O += P . V (V from registers; k-dim = 32 = whole tile) ----
    short8 pf = *(const short8*)(pw + t16 * 64 + ((g * 16) ^ ((t16 >> 2) << 4)));
#pragma unroll
    for (int dt = 0; dt < 8; ++dt)
      acc[dt] = __builtin_amdgcn_mfma_f32_16x16x32_bf16(pf, vcur[dt], acc[dt], 0, 0, 0);

    if (more) {
      asm volatile("s_waitcnt vmcnt(8)" ::: "memory");   // next K staged; V still in flight
#pragma unroll
      for (int dt = 0; dt < 8; ++dt) vcur[dt] = vnext[dt];
    }
    __builtin_amdgcn_s_barrier();             // both waves done reading K[cur]
    __builtin_amdgcn_sched_barrier(0);
    cur ^= 1;
  }

  // ---- deferred row-sum reduction (once) ----
  float lred[4];
#pragma unroll
  for (int r = 0; r < 4; ++r) {
    float v0 = lsum[r];
    v0 += __shfl_xor(v0, 1);
    v0 += __shfl_xor(v0, 2);
    v0 += __shfl_xor(v0, 4);
    v0 += __shfl_xor(v0, 8);
    lred[r] = v0;
  }

  // ---- epilogue ----
  if (nseg == 1) {
#pragma unroll
    for (int r = 0; r < 4; ++r) {
      float inv = 1.0f / lred[r];
#pragma unroll
      for (int dt = 0; dt < 8; ++dt)
        out[((size_t)b * T_DIM + qb16 + 4 * g + r) * D_DIM + dt * 16 + t16] = acc[dt][r] * inv;
    }
  } else {
    int pofs = 0;
    for (int cc = 0; cc < c; ++cc) pofs += ((cc + SEGT) >> 3) - 1;
    const size_t slot = (size_t)b * MLSLOTS_PER_B + pofs + c + s;
    unsigned short* pob = po + slot * 4096;   // 32 rows x 128 bf16
#pragma unroll
    for (int r = 0; r < 4; ++r) {
      int rb = w * 16 + 4 * g + r;            // row within 32-row block
#pragma unroll
      for (int dt = 0; dt < 8; ++dt)
        pob[rb * 128 + dt * 16 + t16] = f2bf(acc[dt][r]);
    }
    if (t16 == 0) {
#pragma unroll
      for (int r = 0; r < 4; ++r) {
        int rb = w * 16 + 4 * g + r;
        ml[slot * 64 + rb] = mrun[r];         // log2 units
        ml[slot * 64 + 32 + rb] = lred[r];
      }
    }
  }
}

// ---------------- combine partials (chunks c >= 8); m in log2 units ----------------
__global__ __launch_bounds__(256) void combine_kernel(
    const unsigned short* __restrict__ po, const float* __restrict__ ml,
    float* __restrict__ out)
{
  const int tid = threadIdx.x;
  const int b = blockIdx.x;
  const int c = SEGT + (int)blockIdx.y;       // 8..63
  const int nt = c + 1;
  const int nseg = (nt + SEGT - 1) >> 3;      // 2..8
  int pofs = 0;
  for (int cc = 0; cc < c; ++cc) pofs += ((cc + SEGT) >> 3) - 1;
  const size_t slot0 = (size_t)b * MLSLOTS_PER_B + pofs + c;

  __shared__ float wgt[32][8];
  if (tid < 32) {
    float M = -1e30f;
    for (int s = 0; s < nseg; ++s)
      M = fmaxf(M, ml[(slot0 + s) * 64 + tid]);
    float L = 0.f;
    for (int s = 0; s < nseg; ++s) {
      float e = exp2f(ml[(slot0 + s) * 64 + tid] - M);
      wgt[tid][s] = e;
      L += e * ml[(slot0 + s) * 64 + 32 + tid];
    }
    float invL = 1.f / L;
    for (int s = 0; s < nseg; ++s) wgt[tid][s] *= invL;
  }
  __syncthreads();

#pragma unroll
  for (int it = 0; it < 2; ++it) {
    int vid = it * 256 + tid;                 // 512 = 32 rows x 16 chunks of 8
    int r = vid >> 4, ch = vid & 15;
    float o[8] = {0.f, 0.f, 0.f, 0.f, 0.f, 0.f, 0.f, 0.f};
    for (int s = 0; s < nseg; ++s) {
      short8 pv = *(const short8*)(po + (slot0 + s) * 4096 + r * 128 + ch * 8);
      float ws = wgt[r][s];
#pragma unroll
      for (int j = 0; j < 8; ++j) o[j] += ws * bf2f((unsigned short)pv[j]);
    }
    float* op = out + ((size_t)b * T_DIM + c * 32 + r) * D_DIM + ch * 8;
    *(float4*)op = (float4){o[0], o[1], o[2], o[3]};
    *(float4*)(op + 4) = (float4){o[4], o[5], o[6], o[7]};
  }
}

extern "C" void kernel_launch(void* const* d_in, const int* in_sizes, int n_in,
                              void* d_out, int out_size, void* d_ws, size_t ws_size,
                              hipStream_t stream) {
  const float* q = (const float*)d_in[0];
  const float* k = (const float*)d_in[1];
  const float* v = (const float*)d_in[2];
  // d_in[3] = mask (causal tril, hardcoded)
  const float* mode = (const float*)d_in[4];
  float* out = (float*)d_out;

  char* ws = (char*)d_ws;
  unsigned short* qbf = (unsigned short*)(ws);                 //  4,194,304
  unsigned short* kbf = (unsigned short*)(ws + 4194304);       //  4,194,304
  unsigned short* vtb = (unsigned short*)(ws + 8388608);       //  4,194,304
  unsigned short* po  = (unsigned short*)(ws + 12582912);      //  8*288 slots * 8KB = 18,874,368
  float*          ml  = (float*)(ws + 31457280);               //  8*288 slots * 256B =  589,824
  // total 32,047,104 B (== confirmed available ws)

  prep_all<<<dim3(B_DIM, T_DIM / 64), 256, 0, stream>>>(q, k, v, mode, qbf, kbf, vtb);
  attn_kernel<<<dim3(B_DIM, 64, SEGT), 128, 0, stream>>>(qbf, kbf, vtb, out, po, ml);
  combine_kernel<<<dim3(B_DIM, 64 - SEGT), 256, 0, stream>>>(po, ml, out);
}

// Round 19
// 53.200 us; speedup vs baseline: 2.7008x; 2.7008x over previous
//
#include <hip/hip_runtime.h>
#include <hip/hip_bf16.h>
#include <cstdint>
#include <cstddef>

// B=8, T=2048, D=128 causal dual-mode attention.
// logits = Qeff . K^T with Qeff[t][d] = -alpha*scale*q[t][d] + (1-alpha)*scale*q[t][(d+1)%D]
// (feature-roll moved from K onto Q), then causal softmax, then @V.
//
// FINAL (= R11, best measured total 53.2 us): 2-wave (128t) blocks, 32 q-rows
// (16/wave), KVBLK=32 single-buffered in 18KB LDS -> 8 blocks/CU. SEGT=8
// split-KV (2304 working blocks), big-c first. Defer-max + deferred-sum
// softmax, exp2 domain, XOR-swizzled K/V/P.

typedef __attribute__((ext_vector_type(8))) short short8;
typedef __attribute__((ext_vector_type(4))) float f32x4;

#define T_DIM 2048
#define D_DIM 128
#define B_DIM 8
#define SEGT 8              // 32-kv tiles per segment
#define POSLOTS_PER_B 224   // sum over c=0..63 of (nseg(c)-1), nseg=ceil((c+1)/8)
#define MLSLOTS_PER_B 288   // sum of nseg(c) = 224 + 64
#define LOG2E 1.4426950408889634f

__device__ __forceinline__ unsigned short f2bf(float f) {
  unsigned u = __builtin_bit_cast(unsigned, f);
  u += 0x7FFFu + ((u >> 16) & 1u);          // RNE
  return (unsigned short)(u >> 16);
}
__device__ __forceinline__ float bf2f(unsigned short u) {
  return __uint_as_float(((unsigned)u) << 16);
}
__device__ __forceinline__ void gload_lds16(const void* g, void* l) {
  __builtin_amdgcn_global_load_lds(
      (const __attribute__((address_space(1))) unsigned int*)g,
      (__attribute__((address_space(3))) unsigned int*)l, 16, 0, 0);
}

// ---------------- fused prepass: K->bf16, Qeff->bf16 (log2e folded), V^T->bf16 ----------------
__global__ __launch_bounds__(256) void prep_all(
    const float* __restrict__ q, const float* __restrict__ k, const float* __restrict__ v,
    const float* __restrict__ modep,
    unsigned short* __restrict__ qbf, unsigned short* __restrict__ kbf,
    unsigned short* __restrict__ vt)
{
  __shared__ unsigned short tile[64 * 136];   // V rows as bf16, pitch 136 shorts
  const int b = blockIdx.x, s0 = blockIdx.y * 64;
  const int tid = threadIdx.x;
  const float alpha = 1.f / (1.f + __expf(-modep[0]));
  const float scale = 0.08838834764831845f;
  const float ca = -alpha * scale * LOG2E, cb = (1.f - alpha) * scale * LOG2E;

#pragma unroll
  for (int u = 0; u < 4; ++u) {
    int c = u * 256 + tid;                    // 1024 chunks = 64 rows x 16
    int r = c >> 4, c8 = c & 15;
    size_t row = (size_t)b * T_DIM + s0 + r;
    float4 ka = *(const float4*)(k + row * D_DIM + c8 * 8);
    float4 kb2 = *(const float4*)(k + row * D_DIM + c8 * 8 + 4);
    short8 ko = { (short)f2bf(ka.x), (short)f2bf(ka.y), (short)f2bf(ka.z), (short)f2bf(ka.w),
                  (short)f2bf(kb2.x), (short)f2bf(kb2.y), (short)f2bf(kb2.z), (short)f2bf(kb2.w) };
    *(short8*)(kbf + row * D_DIM + c8 * 8) = ko;
    const float* qr = q + row * D_DIM;
    float e[9];
    float4 f0 = *(const float4*)(qr + c8 * 8);
    float4 f1 = *(const float4*)(qr + c8 * 8 + 4);
    e[0] = f0.x; e[1] = f0.y; e[2] = f0.z; e[3] = f0.w;
    e[4] = f1.x; e[5] = f1.y; e[6] = f1.z; e[7] = f1.w;
    e[8] = qr[(c8 * 8 + 8) & 127];
    short8 qo;
#pragma unroll
    for (int j = 0; j < 8; ++j) qo[j] = (short)f2bf(ca * e[j] + cb * e[j + 1]);
    *(short8*)(qbf + row * D_DIM + c8 * 8) = qo;
    float4 va = *(const float4*)(v + row * D_DIM + c8 * 8);
    float4 vb2 = *(const float4*)(v + row * D_DIM + c8 * 8 + 4);
    short8 vo = { (short)f2bf(va.x), (short)f2bf(va.y), (short)f2bf(va.z), (short)f2bf(va.w),
                  (short)f2bf(vb2.x), (short)f2bf(vb2.y), (short)f2bf(vb2.z), (short)f2bf(vb2.w) };
    *(short8*)(tile + r * 136 + c8 * 8) = vo;
  }
  __syncthreads();
#pragma unroll
  for (int u = 0; u < 8; ++u) {
    int c = u * 256 + tid;                    // 2048 = 128 d x 16 s-quads
    int d = c >> 4, sq = c & 15;
    ushort4 o = { tile[(sq * 4 + 0) * 136 + d], tile[(sq * 4 + 1) * 136 + d],
                  tile[(sq * 4 + 2) * 136 + d], tile[(sq * 4 + 3) * 136 + d] };
    *(ushort4*)(vt + ((size_t)b * D_DIM + d) * T_DIM + s0 + sq * 4) = o;
  }
}

// ---------------- main attention: 2-wave blocks, 32 q-rows, KVBLK=32 ----------------
// LDS 18,432B: K [32][256B] swz | V [128][64B] swz | P per-wave [16][64B] swz
__global__ __launch_bounds__(128, 4) void attn_kernel(
    const unsigned short* __restrict__ qbf, const unsigned short* __restrict__ kbf,
    const unsigned short* __restrict__ vt, float* __restrict__ out,
    unsigned short* __restrict__ po, float* __restrict__ ml)
{
  __shared__ uint4 smem4[1152];               // 18,432 B
  char* smem = (char*)smem4;
  const int tid = threadIdx.x;
  const int w = tid >> 6, lane = tid & 63;
  const int t16 = lane & 15, g = lane >> 4;
  const int b = blockIdx.x;                   // linear%8==b -> batch pinned to XCD
  const int c = 63 - (int)blockIdx.y;         // 32-row q-chunk, big first
  const int s = blockIdx.z;
  const int nt = c + 1;                       // causal 32-kv tiles
  const int nseg = (nt + SEGT - 1) >> 3;
  if (s >= nseg) return;
  const int t0 = s * SEGT;
  const int t1 = min(nt, t0 + SEGT);
  const int qb16 = c * 32 + w * 16;           // wave's first q-row

  char* kb = smem;                            // 8 KB
  char* vb = smem + 8192;                     // 8 KB
  char* pw = smem + 16384 + w * 1024;         // per-wave P [16][64B], swizzled
  const unsigned short* kbase = kbf + (size_t)b * T_DIM * D_DIM;
  const unsigned short* vbase = vt + (size_t)b * D_DIM * T_DIM;

  // ---- Qeff fragments (A-layout: row=t16, k=dd*32+g*8+i) ----
  short8 qf[4];
  {
    const unsigned short* qr = qbf + ((size_t)b * T_DIM + qb16 + t16) * D_DIM + g * 8;
#pragma unroll
    for (int dd = 0; dd < 4; ++dd) qf[dd] = *(const short8*)(qr + dd * 32);
  }

  f32x4 acc[8];                               // C: row q = 4g+r, col d = 16dt+t16
#pragma unroll
  for (int dt = 0; dt < 8; ++dt) acc[dt] = (f32x4){0.f, 0.f, 0.f, 0.f};
  float mrun[4] = {-1e30f, -1e30f, -1e30f, -1e30f};   // per q-row 4g+r, log2 units
  float lsum[4] = {0.f, 0.f, 0.f, 0.f};

  for (int kt = t0; kt < t1; ++kt) {
    const int kv0 = kt * 32;
    __syncthreads();                          // all waves done reading previous tile
    // ---- stage K tile (32 rows x 256B), inverse-swizzled source ----
#pragma unroll
    for (int u = 0; u < 4; ++u) {
      int s_loc = w * 16 + u * 4 + (lane >> 4);
      int slot = (lane & 15) ^ (s_loc & 7);
      gload_lds16(kbase + (size_t)(kv0 + s_loc) * D_DIM + slot * 8,
                  kb + w * 4096 + u * 1024);
    }
    // ---- stage V tile (128 d-rows x 64B), inverse-swizzled source ----
#pragma unroll
    for (int u = 0; u < 4; ++u) {
      int d_loc = w * 64 + u * 16 + (lane >> 2);
      int vslot = (lane & 3) ^ (d_loc & 3);
      gload_lds16(vbase + (size_t)d_loc * T_DIM + kv0 + vslot * 8,
                  vb + w * 4096 + u * 1024);
    }
    __syncthreads();                          // staged data visible (vmcnt drained)

    // ---- S = Qeff . K^T : sj[jt][r] = S[q=qb16+4g+r][kv=kv0+16jt+t16] ----
    f32x4 sj[2];
#pragma unroll
    for (int jt = 0; jt < 2; ++jt) {
      int srow = jt * 16 + t16;
      int rb = srow * 256, swz = (srow & 7) << 4;
      f32x4 sc = (f32x4){0.f, 0.f, 0.f, 0.f};
#pragma unroll
      for (int dd = 0; dd < 4; ++dd) {
        short8 kf = *(const short8*)(kb + ((rb + dd * 64 + g * 16) ^ swz));
        sc = __builtin_amdgcn_mfma_f32_16x16x32_bf16(qf[dd], kf, sc, 0, 0, 0);
      }
      sj[jt] = sc;
    }

    // ---- causal mask (only the global last tile kt==c can be partial) ----
    if (kt == c) {
#pragma unroll
      for (int jt = 0; jt < 2; ++jt) {
        int sg = kv0 + jt * 16 + t16;
#pragma unroll
        for (int r = 0; r < 4; ++r) {
          int tg = qb16 + 4 * g + r;
          if (sg > tg) sj[jt][r] = -1e30f;
        }
      }
    }

    // ---- defer-max online softmax (log2 domain) ----
    float lm[4];
    int ok = 1;
#pragma unroll
    for (int r = 0; r < 4; ++r) {
      lm[r] = fmaxf(sj[0][r], sj[1][r]);
      ok &= (lm[r] <= mrun[r] + 11.0f);
    }
    if (!__all(ok)) {
#pragma unroll
      for (int r = 0; r < 4; ++r) {
        float tm = lm[r];
        tm = fmaxf(tm, __shfl_xor(tm, 1));
        tm = fmaxf(tm, __shfl_xor(tm, 2));
        tm = fmaxf(tm, __shfl_xor(tm, 4));
        tm = fmaxf(tm, __shfl_xor(tm, 8));
        float mnew = fmaxf(mrun[r], tm);
        float corr = exp2f(mrun[r] - mnew);
        mrun[r] = mnew;
        lsum[r] *= corr;
#pragma unroll
        for (int dt = 0; dt < 8; ++dt) acc[dt][r] *= corr;
      }
    }

    // ---- P = exp2(S-m), per-lane partial sums, P -> LDS (swizzled) ----
#pragma unroll
    for (int jt = 0; jt < 2; ++jt)
#pragma unroll
      for (int r = 0; r < 4; ++r) {
        float p = exp2f(sj[jt][r] - mrun[r]);
        lsum[r] += p;
        int row = 4 * g + r;                  // q-row local
        *(unsigned short*)(pw + row * 64 + ((jt * 32 + t16 * 2) ^ ((row >> 2) << 4))) = f2bf(p);
      }

    // ---- O += P . V (k-dim = 32 = whole tile, 1 MFMA per dt) ----
    short8 pf = *(const short8*)(pw + t16 * 64 + ((g * 16) ^ ((t16 >> 2) << 4)));
#pragma unroll
    for (int dt = 0; dt < 8; ++dt) {
      int d = dt * 16 + t16;
      short8 vf = *(const short8*)(vb + d * 64 + ((g * 16) ^ ((d & 3) << 4)));
      acc[dt] = __builtin_amdgcn_mfma_f32_16x16x32_bf16(pf, vf, acc[dt], 0, 0, 0);
    }
  }

  // ---- deferred row-sum reduction (once) ----
  float lred[4];
#pragma unroll
  for (int r = 0; r < 4; ++r) {
    float v0 = lsum[r];
    v0 += __shfl_xor(v0, 1);
    v0 += __shfl_xor(v0, 2);
    v0 += __shfl_xor(v0, 4);
    v0 += __shfl_xor(v0, 8);
    lred[r] = v0;
  }

  // ---- epilogue ----
  if (nseg == 1) {
#pragma unroll
    for (int r = 0; r < 4; ++r) {
      float inv = 1.0f / lred[r];
#pragma unroll
      for (int dt = 0; dt < 8; ++dt)
        out[((size_t)b * T_DIM + qb16 + 4 * g + r) * D_DIM + dt * 16 + t16] = acc[dt][r] * inv;
    }
  } else {
    int pofs = 0;                             // sum over cc<c of (nseg(cc)-1)
    for (int cc = 0; cc < c; ++cc) pofs += ((cc + SEGT) >> 3) - 1;
    if (s == 0) {
      // seg0 partial (unnormalized f32) lives in out[]
#pragma unroll
      for (int r = 0; r < 4; ++r)
#pragma unroll
        for (int dt = 0; dt < 8; ++dt)
          out[((size_t)b * T_DIM + qb16 + 4 * g + r) * D_DIM + dt * 16 + t16] = acc[dt][r];
    } else {
      unsigned short* pob = po + ((size_t)b * POSLOTS_PER_B + pofs + (s - 1)) * 4096;
#pragma unroll
      for (int r = 0; r < 4; ++r) {
        int rb = w * 16 + 4 * g + r;          // row within 32-row block
#pragma unroll
        for (int dt = 0; dt < 8; ++dt)
          pob[rb * 128 + dt * 16 + t16] = f2bf(acc[dt][r]);
      }
    }
    if (t16 == 0) {
      const size_t mlslot = (size_t)b * MLSLOTS_PER_B + pofs + c + s;
#pragma unroll
      for (int r = 0; r < 4; ++r) {
        int rb = w * 16 + 4 * g + r;
        ml[mlslot * 64 + rb] = mrun[r];       // log2 units
        ml[mlslot * 64 + 32 + rb] = lred[r];
      }
    }
  }
}

// ---------------- combine partials (chunks c >= 8); m in log2 units ----------------
__global__ __launch_bounds__(256) void combine_kernel(
    const unsigned short* __restrict__ po, const float* __restrict__ ml,
    float* __restrict__ out)
{
  const int tid = threadIdx.x;
  const int b = blockIdx.x;
  const int c = SEGT + (int)blockIdx.y;       // 8..63
  const int nt = c + 1;
  const int nseg = (nt + SEGT - 1) >> 3;      // 2..8
  int pofs = 0;
  for (int cc = 0; cc < c; ++cc) pofs += ((cc + SEGT) >> 3) - 1;
  const size_t mlbase = (size_t)b * MLSLOTS_PER_B + pofs + c;
  const size_t pobase = (size_t)b * POSLOTS_PER_B + pofs;

  __shared__ float wgt[32][8];
  if (tid < 32) {
    float M = -1e30f;
    for (int s = 0; s < nseg; ++s)
      M = fmaxf(M, ml[(mlbase + s) * 64 + tid]);
    float L = 0.f;
    for (int s = 0; s < nseg; ++s) {
      float e = exp2f(ml[(mlbase + s) * 64 + tid] - M);
      wgt[tid][s] = e;
      L += e * ml[(mlbase + s) * 64 + 32 + tid];
    }
    float invL = 1.f / L;
    for (int s = 0; s < nseg; ++s) wgt[tid][s] *= invL;
  }
  __syncthreads();

#pragma unroll
  for (int it = 0; it < 2; ++it) {
    int vid = it * 256 + tid;                 // 512 = 32 rows x 16 chunks of 8
    int r = vid >> 4, ch = vid & 15;
    float* op = out + ((size_t)b * T_DIM + c * 32 + r) * D_DIM + ch * 8;
    float4 a0 = *(const float4*)op;
    float4 a1 = *(const float4*)(op + 4);
    float w0 = wgt[r][0];
    float o[8] = { w0 * a0.x, w0 * a0.y, w0 * a0.z, w0 * a0.w,
                   w0 * a1.x, w0 * a1.y, w0 * a1.z, w0 * a1.w };
    for (int s = 1; s < nseg; ++s) {
      short8 pv = *(const short8*)(po + (pobase + s - 1) * 4096 + r * 128 + ch * 8);
      float ws = wgt[r][s];
#pragma unroll
      for (int j = 0; j < 8; ++j) o[j] += ws * bf2f((unsigned short)pv[j]);
    }
    *(float4*)op = (float4){o[0], o[1], o[2], o[3]};
    *(float4*)(op + 4) = (float4){o[4], o[5], o[6], o[7]};
  }
}

extern "C" void kernel_launch(void* const* d_in, const int* in_sizes, int n_in,
                              void* d_out, int out_size, void* d_ws, size_t ws_size,
                              hipStream_t stream) {
  const float* q = (const float*)d_in[0];
  const float* k = (const float*)d_in[1];
  const float* v = (const float*)d_in[2];
  // d_in[3] = mask (causal tril, hardcoded)
  const float* mode = (const float*)d_in[4];
  float* out = (float*)d_out;

  char* ws = (char*)d_ws;
  unsigned short* qbf = (unsigned short*)(ws);                 //  4,194,304
  unsigned short* kbf = (unsigned short*)(ws + 4194304);       //  4,194,304
  unsigned short* vtb = (unsigned short*)(ws + 8388608);       //  4,194,304
  unsigned short* po  = (unsigned short*)(ws + 12582912);      //  8*224 slots * 8KB = 14,680,064
  float*          ml  = (float*)(ws + 27262976);               //  8*288 slots * 256B =  589,824
  // total 27,852,800 B (<= 32,047,104 confirmed available)

  prep_all<<<dim3(B_DIM, T_DIM / 64), 256, 0, stream>>>(q, k, v, mode, qbf, kbf, vtb);
  attn_kernel<<<dim3(B_DIM, 64, SEGT), 128, 0, stream>>>(qbf, kbf, vtb, out, po, ml);
  combine_kernel<<<dim3(B_DIM, 64 - SEGT), 256, 0, stream>>>(po, ml, out);
}